// Round 6
// baseline (116.222 us; speedup 1.0000x reference)
//
#include <hip/hip_runtime.h>
#include <hip/hip_bf16.h>
#include <hip/hip_cooperative_groups.h>

// PairRE scoring: out[b,n] = -|| t_hat[n]*rt[b] - h_hat[b]*rh[b] ||_2
// B=512, N=2048, E=256.
//
// x(b,n) = dot([T^2 | T]_n , [rt^2 | -2*rt*Hh]_b) + c_b,
//   T = t/||t||, Hh = (h/||h||)*rh, c_b = ||Hh_b||^2.
//
// R6: ONE cooperative kernel (256 blocks, 1024 waves), grid.sync between:
//  phase 1: 2560 wave-tasks build bf16 operands in MFMA-fragment-packed ws
//           (R4's verified prep body; coalesced uint4 stores).
//  phase 2: wave tile 32(b) x 32(n): 2 A-streams x 2 T-streams -> 4 MFMAs
//           per 4KB loaded (1KB/MFMA, was 1.5KB in R4). No LDS anywhere.
// Fallback (coop launch unavailable): same bodies as two plain dispatches.

#define B_DIM 512
#define N_DIM 2048
#define E_DIM 256
#define K_DIM 512
#define NSTEP 16        // K/32 MFMA k-steps
#define FRAG_US 512     // ushorts per packed fragment (64 lanes * 8)

namespace cg = cooperative_groups;

typedef __attribute__((ext_vector_type(8))) __bf16 bf16x8;
typedef __attribute__((ext_vector_type(4))) float f32x4;

__device__ inline ushort f2bf(float x) {
    __hip_bfloat16 h = __float2bfloat16(x);   // RNE
    union { __hip_bfloat16 b; ushort u; } cv; cv.b = h; return cv.u;
}

__device__ inline float wave_sum(float v) {
#pragma unroll
    for (int m = 1; m < 64; m <<= 1) v += __shfl_xor(v, m, 64);
    return v;
}

// ---- prep one row-task (R4-verified body; packed addr ((g*16+s)*64+q*16+m)*8)
__device__ inline void prep_row(int w, int lane,
        const float* __restrict__ head, const float* __restrict__ tail,
        const float* __restrict__ rel,  const int* __restrict__ rid,
        ushort* __restrict__ Tbig, ushort* __restrict__ Abig,
        float* __restrict__ cvec) {
    const int s_ = lane >> 2, q = lane & 3;
    const int k0 = lane * 8;
    const bool sqr = (k0 < E_DIM);
    const int e0 = k0 & (E_DIM - 1);

    if (w < N_DIM) {
        const int n = w;
        const float* row = tail + (size_t)n * E_DIM;
        const float4 v4 = ((const float4*)row)[lane];
        const float s = wave_sum(v4.x * v4.x + v4.y * v4.y + v4.z * v4.z + v4.w * v4.w);
        const float inv = 1.0f / fmaxf(sqrtf(s), 1e-12f);
        const float4 f0 = *(const float4*)(row + e0);
        const float4 f1 = *(const float4*)(row + e0 + 4);
        const float v[8] = {f0.x, f0.y, f0.z, f0.w, f1.x, f1.y, f1.z, f1.w};
        ushort u[8];
#pragma unroll
        for (int j = 0; j < 8; ++j) {
            float x = v[j] * inv;
            if (sqr) x *= x;
            u[j] = f2bf(x);
        }
        const int g = n >> 4, m = n & 15;
        *(uint4*)(Tbig + (size_t)((g * 16 + s_) * 64 + q * 16 + m) * 8) = *(const uint4*)u;
    } else {
        const int b = w - N_DIM;
        const int id = rid[b];
        const float* hrow  = head + (size_t)b * E_DIM;
        const float* rhrow = rel + (size_t)id * (2 * E_DIM);
        const float* rtrow = rhrow + E_DIM;
        const float4 h4  = ((const float4*)hrow)[lane];
        const float4 rh4 = ((const float4*)rhrow)[lane];
        const float s1 = wave_sum(h4.x * h4.x + h4.y * h4.y + h4.z * h4.z + h4.w * h4.w);
        const float inv = 1.0f / fmaxf(sqrtf(s1), 1e-12f);
        const float p0 = h4.x * inv * rh4.x, p1 = h4.y * inv * rh4.y;
        const float p2 = h4.z * inv * rh4.z, p3 = h4.w * inv * rh4.w;
        const float s2 = wave_sum(p0 * p0 + p1 * p1 + p2 * p2 + p3 * p3);
        if (lane == 0) cvec[b] = s2;

        const float4 rt0 = *(const float4*)(rtrow + e0);
        const float4 rt1 = *(const float4*)(rtrow + e0 + 4);
        const float rt[8] = {rt0.x, rt0.y, rt0.z, rt0.w, rt1.x, rt1.y, rt1.z, rt1.w};
        float v[8];
        if (sqr) {
#pragma unroll
            for (int j = 0; j < 8; ++j) v[j] = rt[j] * rt[j];
        } else {
            const float4 h0 = *(const float4*)(hrow + e0);
            const float4 h1 = *(const float4*)(hrow + e0 + 4);
            const float4 r0 = *(const float4*)(rhrow + e0);
            const float4 r1 = *(const float4*)(rhrow + e0 + 4);
            const float hh[8] = {h0.x, h0.y, h0.z, h0.w, h1.x, h1.y, h1.z, h1.w};
            const float rr[8] = {r0.x, r0.y, r0.z, r0.w, r1.x, r1.y, r1.z, r1.w};
#pragma unroll
            for (int j = 0; j < 8; ++j) v[j] = -2.0f * rt[j] * (hh[j] * inv * rr[j]);
        }
        ushort u[8];
#pragma unroll
        for (int j = 0; j < 8; ++j) u[j] = f2bf(v[j]);
        const int g = b >> 4, m = b & 15;
        *(uint4*)(Abig + (size_t)((g * 16 + s_) * 64 + q * 16 + m) * 8) = *(const uint4*)u;
    }
}

// ---- score one 32x32 wave-tile g in [0,1024): p_b = g>>6, p_n = g&63 ----
__device__ inline void score_tile(int g, int lane,
        const ushort* __restrict__ Tbig, const ushort* __restrict__ Abig,
        const float* __restrict__ cvec, float* __restrict__ out) {
    const int p_b = g >> 6, p_n = g & 63;
    const ushort* A0 = Abig + (size_t)(p_b * 2) * NSTEP * FRAG_US + lane * 8;
    const ushort* A1 = A0 + (size_t)NSTEP * FRAG_US;
    const ushort* T0 = Tbig + (size_t)(p_n * 2) * NSTEP * FRAG_US + lane * 8;
    const ushort* T1 = T0 + (size_t)NSTEP * FRAG_US;

    f32x4 acc00 = {0,0,0,0}, acc01 = {0,0,0,0}, acc10 = {0,0,0,0}, acc11 = {0,0,0,0};

    bf16x8 a0 = *(const bf16x8*)(A0);
    bf16x8 a1 = *(const bf16x8*)(A1);
    bf16x8 t0 = *(const bf16x8*)(T0);
    bf16x8 t1 = *(const bf16x8*)(T1);
#pragma unroll
    for (int s = 0; s < NSTEP - 1; ++s) {
        const bf16x8 a0n = *(const bf16x8*)(A0 + (s + 1) * FRAG_US);
        const bf16x8 a1n = *(const bf16x8*)(A1 + (s + 1) * FRAG_US);
        const bf16x8 t0n = *(const bf16x8*)(T0 + (s + 1) * FRAG_US);
        const bf16x8 t1n = *(const bf16x8*)(T1 + (s + 1) * FRAG_US);
        acc00 = __builtin_amdgcn_mfma_f32_16x16x32_bf16(a0, t0, acc00, 0, 0, 0);
        acc01 = __builtin_amdgcn_mfma_f32_16x16x32_bf16(a0, t1, acc01, 0, 0, 0);
        acc10 = __builtin_amdgcn_mfma_f32_16x16x32_bf16(a1, t0, acc10, 0, 0, 0);
        acc11 = __builtin_amdgcn_mfma_f32_16x16x32_bf16(a1, t1, acc11, 0, 0, 0);
        a0 = a0n; a1 = a1n; t0 = t0n; t1 = t1n;
    }
    acc00 = __builtin_amdgcn_mfma_f32_16x16x32_bf16(a0, t0, acc00, 0, 0, 0);
    acc01 = __builtin_amdgcn_mfma_f32_16x16x32_bf16(a0, t1, acc01, 0, 0, 0);
    acc10 = __builtin_amdgcn_mfma_f32_16x16x32_bf16(a1, t0, acc10, 0, 0, 0);
    acc11 = __builtin_amdgcn_mfma_f32_16x16x32_bf16(a1, t1, acc11, 0, 0, 0);

    const int ml = lane & 15, q = lane >> 4;
    const int bb0 = p_b * 32, nn0 = p_n * 32;
#pragma unroll
    for (int r = 0; r < 4; ++r) {
        const int b_lo = bb0 + q * 4 + r;
        const int b_hi = b_lo + 16;
        const float cb_lo = cvec[b_lo];
        const float cb_hi = cvec[b_hi];
        out[(size_t)b_lo * N_DIM + nn0 + ml]      = -sqrtf(fmaxf(acc00[r] + cb_lo, 0.f));
        out[(size_t)b_lo * N_DIM + nn0 + 16 + ml] = -sqrtf(fmaxf(acc01[r] + cb_lo, 0.f));
        out[(size_t)b_hi * N_DIM + nn0 + ml]      = -sqrtf(fmaxf(acc10[r] + cb_hi, 0.f));
        out[(size_t)b_hi * N_DIM + nn0 + 16 + ml] = -sqrtf(fmaxf(acc11[r] + cb_hi, 0.f));
    }
}

// ---------------- cooperative fused kernel: 256 blocks x 256 threads ----------------
__global__ __launch_bounds__(256) void pairre_coop(
        const float* __restrict__ head, const float* __restrict__ tail,
        const float* __restrict__ rel,  const int* __restrict__ rid,
        ushort* __restrict__ Tbig, ushort* __restrict__ Abig,
        float* __restrict__ cvec, float* __restrict__ out) {
    const int lane = threadIdx.x & 63, wv = threadIdx.x >> 6;
    const int gw = blockIdx.x * 4 + wv;          // 0..1023
    // phase 1: tasks gw, gw+1024, gw+2048 (last only if gw < 512)
    prep_row(gw, lane, head, tail, rel, rid, Tbig, Abig, cvec);
    prep_row(gw + 1024, lane, head, tail, rel, rid, Tbig, Abig, cvec);
    if (gw < 512)
        prep_row(gw + 2048, lane, head, tail, rel, rid, Tbig, Abig, cvec);

    cg::this_grid().sync();

    // phase 2: one 32x32 tile per wave
    score_tile(gw, lane, Tbig, Abig, cvec, out);
}

// ---------------- fallback: two plain dispatches (R4 structure) ----------------
__global__ __launch_bounds__(256) void prep_kernel(
        const float* __restrict__ head, const float* __restrict__ tail,
        const float* __restrict__ rel,  const int* __restrict__ rid,
        ushort* __restrict__ Tbig, ushort* __restrict__ Abig,
        float* __restrict__ cvec) {
    const int lane = threadIdx.x & 63, wv = threadIdx.x >> 6;
    prep_row(blockIdx.x * 4 + wv, lane, head, tail, rel, rid, Tbig, Abig, cvec);
}

__global__ __launch_bounds__(256) void score_kernel(
        const ushort* __restrict__ Tbig, const ushort* __restrict__ Abig,
        const float* __restrict__ cvec, float* __restrict__ out) {
    const int lane = threadIdx.x & 63, wv = threadIdx.x >> 6;
    score_tile(blockIdx.x * 4 + wv, lane, Tbig, Abig, cvec, out);
}

extern "C" void kernel_launch(void* const* d_in, const int* in_sizes, int n_in,
                              void* d_out, int out_size, void* d_ws, size_t ws_size,
                              hipStream_t stream) {
    const float* head = (const float*)d_in[0];
    const float* tail = (const float*)d_in[1];
    const float* rel  = (const float*)d_in[2];
    const int*   rid  = (const int*)d_in[3];
    float* out = (float*)d_out;

    ushort* Tbig = (ushort*)d_ws;                                  // 2 MB
    ushort* Abig = Tbig + (size_t)N_DIM * K_DIM;                   // 512 KB
    float*  cvec = (float*)(Abig + (size_t)B_DIM * K_DIM);         // 2 KB

    void* args[] = { (void*)&head, (void*)&tail, (void*)&rel, (void*)&rid,
                     (void*)&Tbig, (void*)&Abig, (void*)&cvec, (void*)&out };
    hipError_t e = hipLaunchCooperativeKernel((const void*)pairre_coop,
                                              dim3(256), dim3(256), args, 0, stream);
    if (e != hipSuccess) {
        // two-dispatch fallback (identical math)
        prep_kernel<<<640, 256, 0, stream>>>(head, tail, rel, rid, Tbig, Abig, cvec);
        score_kernel<<<256, 256, 0, stream>>>(Tbig, Abig, cvec, out);
    }
}